// Round 7
// baseline (261.365 us; speedup 1.0000x reference)
//
#include <hip/hip_runtime.h>
#include <stdint.h>

#define BB 4
#define NN 2048
#define CC 768
#define HH 12
#define DD 64
#define QSCALE 0.18033688011112042f   // D^-0.5 * log2(e), folded into Q

typedef __attribute__((ext_vector_type(2))) float f32x2;
typedef __attribute__((ext_vector_type(4))) float f32x4;
typedef __attribute__((ext_vector_type(16))) float f32x16;
typedef __attribute__((ext_vector_type(8))) short s16x8;

__device__ __forceinline__ unsigned short f2bf(float f){
  unsigned int x = __float_as_uint(f);
  x += 0x7fffu + ((x >> 16) & 1u);          // round-to-nearest-even
  return (unsigned short)(x >> 16);
}

__device__ __forceinline__ f32x4 mfma16(s16x8 a, s16x8 b, f32x4 c){
  return __builtin_amdgcn_mfma_f32_16x16x32_bf16(a, b, c, 0, 0, 0);
}
__device__ __forceinline__ f32x16 mfma32(s16x8 a, s16x8 b, f32x16 c){
  return __builtin_amdgcn_mfma_f32_32x32x16_bf16(a, b, c, 0, 0, 0);
}

__device__ __forceinline__ float fexp2(float x){
#if __has_builtin(__builtin_amdgcn_exp2f)
  return __builtin_amdgcn_exp2f(x);
#else
  float r; asm("v_exp_f32 %0, %1\n\ts_nop 1" : "=v"(r) : "v"(x)); return r;
#endif
}

__device__ __forceinline__ void gld16(void* lds, const void* g){
  __builtin_amdgcn_global_load_lds(
      (const __attribute__((address_space(1))) unsigned int*)g,
      (__attribute__((address_space(3))) unsigned int*)lds, 16, 0, 0);
}

// ---- prep: xm = bf16(x * mask_row) --------------------------------------
__global__ void prep_x(const float* __restrict__ x, const float* __restrict__ mask,
                       unsigned short* __restrict__ xm){
  int i = blockIdx.x * 256 + threadIdx.x;          // float4 group index
  float4 v = ((const float4*)x)[i];
  float m = mask[i / 192];                         // 768/4 = 192 groups per row
  ushort4 o;
  o.x = f2bf(v.x * m); o.y = f2bf(v.y * m);
  o.z = f2bf(v.z * m); o.w = f2bf(v.w * m);
  *(ushort4*)&xm[i * 4] = o;
}

// ---- prep: cast weights to bf16 -----------------------------------------
__global__ void prep_w(const float* __restrict__ wq, const float* __restrict__ wp,
                       unsigned short* __restrict__ oq, unsigned short* __restrict__ op){
  int i = blockIdx.x * 256 + threadIdx.x;
  const int nq = (3 * CC * CC) / 4;
  const float4* s; unsigned short* d; int j;
  if (i < nq){ s = (const float4*)wq; d = oq; j = i; }
  else       { s = (const float4*)wp; d = op; j = i - nq; }
  float4 v = s[j];
  ushort4 o;
  o.x = f2bf(v.x); o.y = f2bf(v.y); o.z = f2bf(v.z); o.w = f2bf(v.w);
  *(ushort4*)&d[j * 4] = o;
}

// ---- Z[b] = count of masked tokens in batch b ---------------------------
__global__ void zprep(const float* __restrict__ mask, float* __restrict__ zb){
  int b = blockIdx.x, t = threadIdx.x;
  float s = 0.f;
  for (int i = t; i < NN; i += 256) s += mask[b * NN + i];
  #pragma unroll
  for (int off = 1; off < 64; off <<= 1) s += __shfl_xor(s, off);
  __shared__ float part[4];
  if ((t & 63) == 0) part[t >> 6] = s;
  __syncthreads();
  if (t == 0) zb[b] = (float)NN - (part[0] + part[1] + part[2] + part[3]);
}

// ---- C = A(row-major [M,K]) * B^T (B row-major [Nn,K]), bf16 MFMA -------
template<int MODE>
__global__ __launch_bounds__(256) void gemm_bt(
    const unsigned short* __restrict__ A, const unsigned short* __restrict__ Bw,
    int Nn, int K,
    unsigned short* __restrict__ Qg, unsigned short* __restrict__ Kg,
    unsigned short* __restrict__ Vtg, float* __restrict__ Outg)
{
  __shared__ __align__(16) unsigned short As[128 * 32];
  __shared__ __align__(16) unsigned short Bs[128 * 32];
  const int t = threadIdx.x, lane = t & 63, wid = t >> 6;
  const int wr = wid >> 1, wc = wid & 1;
  const int bm = blockIdx.x, bn = blockIdx.y;
  const unsigned short* Ag = A  + (size_t)bm * 128 * K;
  const unsigned short* Bg = Bw + (size_t)bn * 128 * K;
  f32x4 acc[4][4] = {};
  const int srow = wid * 32 + (lane >> 2);
  const int scol = (lane & 3) * 8;
  char* AsB = (char*)As; char* BsB = (char*)Bs;
  const int ar = wr * 64 + (lane & 15);
  const int br = wc * 64 + (lane & 15);
  const int kk = (lane >> 4) * 8;

  for (int k0 = 0; k0 < K; k0 += 32){
    __syncthreads();
    gld16(AsB + wid * 2048        + lane * 16, Ag + (size_t)srow * K        + k0 + scol);
    gld16(AsB + wid * 2048 + 1024 + lane * 16, Ag + (size_t)(srow + 16) * K + k0 + scol);
    gld16(BsB + wid * 2048        + lane * 16, Bg + (size_t)srow * K        + k0 + scol);
    gld16(BsB + wid * 2048 + 1024 + lane * 16, Bg + (size_t)(srow + 16) * K + k0 + scol);
    __syncthreads();
    s16x8 af[4], bf[4];
    #pragma unroll
    for (int mi = 0; mi < 4; ++mi) af[mi] = *(const s16x8*)&As[(ar + mi * 16) * 32 + kk];
    #pragma unroll
    for (int ni = 0; ni < 4; ++ni) bf[ni] = *(const s16x8*)&Bs[(br + ni * 16) * 32 + kk];
    #pragma unroll
    for (int mi = 0; mi < 4; ++mi)
      #pragma unroll
      for (int ni = 0; ni < 4; ++ni)
        acc[mi][ni] = mfma16(af[mi], bf[ni], acc[mi][ni]);
  }

  const int row0 = bm * 128 + wr * 64;
  const int col0 = bn * 128 + wc * 64;
  if (MODE == 0){
    #pragma unroll
    for (int ni = 0; ni < 4; ++ni){
      int col = col0 + ni * 16 + (lane & 15);
      int s = col / CC, rem = col - s * CC;
      int h = rem >> 6, d = rem & 63;
      #pragma unroll
      for (int mi = 0; mi < 4; ++mi){
        int rbase = row0 + mi * 16 + ((lane >> 4) << 2);
        int b = rbase >> 11, tok0 = rbase & 2047;
        if (s == 2){
          ushort4 pk;
          pk.x = f2bf(acc[mi][ni][0]); pk.y = f2bf(acc[mi][ni][1]);
          pk.z = f2bf(acc[mi][ni][2]); pk.w = f2bf(acc[mi][ni][3]);
          *(ushort4*)&Vtg[((size_t)((b * HH + h) * DD + d) << 11) + tok0] = pk;
        } else {
          unsigned short* dst = (s == 0) ? Qg : Kg;
          float sc = (s == 0) ? QSCALE : 1.0f;
          size_t base = (((size_t)(b * HH + h) << 11) + tok0) * DD + d;
          #pragma unroll
          for (int r = 0; r < 4; ++r) dst[base + (size_t)r * DD] = f2bf(acc[mi][ni][r] * sc);
        }
      }
    }
  } else {
    #pragma unroll
    for (int ni = 0; ni < 4; ++ni){
      int col = col0 + ni * 16 + (lane & 15);
      #pragma unroll
      for (int mi = 0; mi < 4; ++mi){
        int rbase = row0 + mi * 16 + ((lane >> 4) << 2);
        #pragma unroll
        for (int r = 0; r < 4; ++r) Outg[(size_t)(rbase + r) * Nn + col] = acc[mi][ni][r];
      }
    }
  }
}

// exp2 + RNE pack via v_cvt_pk_bf16_f32; l accumulated as float2 (v_pk_add_f32)
__device__ __forceinline__ void packrow2(float s0, float s1, float s2, float s3,
                                         f32x2& l2, unsigned& d0, unsigned& d1){
  float p0 = fexp2(s0), p1 = fexp2(s1), p2 = fexp2(s2), p3 = fexp2(s3);
  f32x2 a = {p0, p1}, b = {p2, p3};
  l2 += a + b;
  asm("v_cvt_pk_bf16_f32 %0, %1, %2" : "=v"(d0) : "v"(p0), "v"(p1));
  asm("v_cvt_pk_bf16_f32 %0, %1, %2" : "=v"(d1) : "v"(p2), "v"(p3));
}

// ---- flash attention: ZERO-LDS, ZERO-BARRIER -----------------------------
// K/V is L2-resident (512 KB per (b,h); XCD swizzle keeps ~3 MB per XCD L2 —
// r6 FETCH=18.5 MB proved it). LDS staging + barriers were pure overhead
// (m169). Each wave: 32 q-rows, full 64-kv tile, fragments straight from
// global (L1/L2). No __syncthreads anywhere. r2's bench-verified fragment
// math: swapped QK^T (col=q), permlane32 P-exchange, no-max softmax + Z_b.
__global__ __launch_bounds__(256, 2) void attn_kernel(
    const unsigned short* __restrict__ Qg, const unsigned short* __restrict__ Kg,
    const unsigned short* __restrict__ Vtg, const float* __restrict__ mask,
    const float* __restrict__ zb, unsigned short* __restrict__ Og)
{
  const int t = threadIdx.x, lane = t & 63, w = t >> 6;
  const int lo5 = lane & 31, hi = lane >> 5, hi8 = hi * 8;

  // XCD-chunked swizzle: 768 blocks = 8 x 96; all 16 q-tiles of a (b,h)
  // group land on one XCD -> K/V L2-resident per XCD.
  int g = blockIdx.x + (NN / 128) * blockIdx.y;
  g = (g & 7) * 96 + (g >> 3);
  const int qt = g & 15, bh = g >> 4;
  const int b = bh / HH, h = bh % HH;
  const unsigned short* Qb  = Qg  + (size_t)bh * NN * DD;
  const unsigned short* Kb  = Kg  + (size_t)bh * NN * DD;
  const unsigned short* Vtb = Vtg + (size_t)bh * DD * NN;

  // Q fragments (B-operand of swapped QK^T): Q[q=lo5][ds*16 + hi8 + j]
  const int qrow = qt * 128 + w * 32 + lo5;
  s16x8 qf[4];
  #pragma unroll
  for (int ds = 0; ds < 4; ++ds)
    qf[ds] = *(const s16x8*)&Qb[(size_t)qrow * DD + ds * 16 + hi8];

  f32x16 o0 = {}, o1 = {};
  f32x2 la = {0.f, 0.f};

  for (int tt = 0; tt < NN / 64; ++tt){
    const int kv0 = tt * 64;

    // fragments straight from global (L1/L2-served)
    s16x8 kf0[4], kf1[4], vfA[4], vfB[4];
    #pragma unroll
    for (int ds = 0; ds < 4; ++ds){
      kf0[ds] = *(const s16x8*)&Kb[(size_t)(kv0 + lo5) * DD + ds * 16 + hi8];
      kf1[ds] = *(const s16x8*)&Kb[(size_t)(kv0 + 32 + lo5) * DD + ds * 16 + hi8];
    }
    #pragma unroll
    for (int sl = 0; sl < 4; ++sl){
      vfA[sl] = *(const s16x8*)&Vtb[(size_t)lo5 * NN + kv0 + sl * 16 + hi8];
      vfB[sl] = *(const s16x8*)&Vtb[(size_t)(32 + lo5) * NN + kv0 + sl * 16 + hi8];
    }

    // QK^T swapped: S^T[kv][q], col = q = lo5; s0 = kv 0..31, s1 = kv 32..63
    f32x16 s0 = {}, s1 = {};
    __builtin_amdgcn_s_setprio(1);
    #pragma unroll
    for (int ds = 0; ds < 4; ++ds){
      s0 = mfma32(kf0[ds], qf[ds], s0);
      s1 = mfma32(kf1[ds], qf[ds], s1);
    }
    __builtin_amdgcn_s_setprio(0);

    // p = exp2(s); pack to bf16 dwords; accumulate l
    unsigned pdw[16];
    #pragma unroll
    for (int c = 0; c < 4; ++c){
      packrow2(s0[4*c+0], s0[4*c+1], s0[4*c+2], s0[4*c+3], la, pdw[2*c+0], pdw[2*c+1]);
      packrow2(s1[4*c+0], s1[4*c+1], s1[4*c+2], s1[4*c+3], la, pdw[8+2*c+0], pdw[8+2*c+1]);
    }

    // P-exchange (permlane32_swap) + PV
    __builtin_amdgcn_s_setprio(1);
    #pragma unroll
    for (int sl = 0; sl < 4; ++sl){
      const int base = (sl >> 1) * 8 + (sl & 1) * 4;
      unsigned X0 = pdw[base + 0], X1 = pdw[base + 1];
      unsigned Y0 = pdw[base + 2], Y1 = pdw[base + 3];
      asm("s_nop 0\n\tv_permlane32_swap_b32 %0, %1" : "+v"(X0), "+v"(Y0));
      asm("s_nop 0\n\tv_permlane32_swap_b32 %0, %1" : "+v"(X1), "+v"(Y1));
      union { unsigned u[4]; s16x8 v; } pa;
      pa.u[0] = X0; pa.u[1] = X1; pa.u[2] = Y0; pa.u[3] = Y1;
      o0 = mfma32(pa.v, vfA[sl], o0);
      o1 = mfma32(pa.v, vfB[sl], o1);
    }
    __builtin_amdgcn_s_setprio(0);
  }

  // epilogue: l = sum(exp) - Z_b ; O *= mask_q / l ; write [B,N,H*D] bf16
  float lfull = la.x + la.y;
  lfull += __shfl_xor(lfull, 32);
  float Zb = zb[b];
  #pragma unroll
  for (int i = 0; i < 16; ++i){
    int q_ = (i & 3) + 8 * (i >> 2) + 4 * hi;
    int qg = qt * 128 + w * 32 + q_;
    float lq = __shfl(lfull, q_) - Zb;
    float mq = mask[b * NN + qg];
    float inv = (mq != 0.f) ? (mq / lq) : 0.f;
    size_t base = ((size_t)b * NN + qg) * CC + h * DD + lo5;
    Og[base]      = f2bf(o0[i] * inv);
    Og[base + 32] = f2bf(o1[i] * inv);
  }
}

extern "C" void kernel_launch(void* const* d_in, const int* in_sizes, int n_in,
                              void* d_out, int out_size, void* d_ws, size_t ws_size,
                              hipStream_t stream){
  const float* x     = (const float*)d_in[0];
  const float* mask  = (const float*)d_in[1];
  const float* wqkv  = (const float*)d_in[2];
  const float* wproj = (const float*)d_in[3];
  float* out = (float*)d_out;
  char* ws = (char*)d_ws;
  size_t off = 0;
  auto alloc = [&](size_t bytes) -> void* {
    void* p = ws + off; off += (bytes + 255) & ~(size_t)255; return p;
  };
  unsigned short* xm  = (unsigned short*)alloc((size_t)BB * NN * CC * 2);
  unsigned short* wqb = (unsigned short*)alloc((size_t)3 * CC * CC * 2);
  unsigned short* wpb = (unsigned short*)alloc((size_t)CC * CC * 2);
  unsigned short* Qg  = (unsigned short*)alloc((size_t)BB * HH * NN * DD * 2);
  unsigned short* Kg  = (unsigned short*)alloc((size_t)BB * HH * NN * DD * 2);
  unsigned short* Vtg = (unsigned short*)alloc((size_t)BB * HH * NN * DD * 2);
  unsigned short* Og  = (unsigned short*)alloc((size_t)BB * NN * CC * 2);
  float* zbuf         = (float*)alloc(BB * sizeof(float));

  hipLaunchKernelGGL(prep_x, dim3((BB * NN * CC / 4) / 256), dim3(256), 0, stream,
                     x, mask, xm);
  hipLaunchKernelGGL(prep_w, dim3(((3 * CC * CC + CC * CC) / 4) / 256), dim3(256), 0, stream,
                     wqkv, wproj, wqb, wpb);
  hipLaunchKernelGGL(zprep, dim3(BB), dim3(256), 0, stream, mask, zbuf);
  hipLaunchKernelGGL(gemm_bt<0>, dim3(BB * NN / 128, 3 * CC / 128), dim3(256), 0, stream,
                     xm, wqb, 3 * CC, CC, Qg, Kg, Vtg, (float*)nullptr);
  hipLaunchKernelGGL(attn_kernel, dim3(NN / 128, BB * HH), dim3(256), 0, stream,
                     Qg, Kg, Vtg, mask, zbuf, Og);
  hipLaunchKernelGGL(gemm_bt<1>, dim3(BB * NN / 128, CC / 128), dim3(256), 0, stream,
                     Og, wpb, CC, CC, (unsigned short*)nullptr, (unsigned short*)nullptr,
                     (unsigned short*)nullptr, out);
}

// Round 8
// 142.140 us; speedup vs baseline: 1.8388x; 1.8388x over previous
//
#include <hip/hip_runtime.h>
#include <stdint.h>

#define BB 4
#define NN 2048
#define CC 768
#define HH 12
#define DD 64
#define QSCALE 0.18033688011112042f   // D^-0.5 * log2(e), folded into Q

typedef __attribute__((ext_vector_type(2))) float f32x2;
typedef __attribute__((ext_vector_type(4))) float f32x4;
typedef __attribute__((ext_vector_type(16))) float f32x16;
typedef __attribute__((ext_vector_type(8))) short s16x8;

__device__ __forceinline__ unsigned short f2bf(float f){
  unsigned int x = __float_as_uint(f);
  x += 0x7fffu + ((x >> 16) & 1u);          // round-to-nearest-even
  return (unsigned short)(x >> 16);
}

__device__ __forceinline__ f32x4 mfma16(s16x8 a, s16x8 b, f32x4 c){
  return __builtin_amdgcn_mfma_f32_16x16x32_bf16(a, b, c, 0, 0, 0);
}
__device__ __forceinline__ f32x16 mfma32(s16x8 a, s16x8 b, f32x16 c){
  return __builtin_amdgcn_mfma_f32_32x32x16_bf16(a, b, c, 0, 0, 0);
}

__device__ __forceinline__ float fexp2(float x){
#if __has_builtin(__builtin_amdgcn_exp2f)
  return __builtin_amdgcn_exp2f(x);
#else
  float r; asm("v_exp_f32 %0, %1\n\ts_nop 1" : "=v"(r) : "v"(x)); return r;
#endif
}

__device__ __forceinline__ void gld16(void* lds, const void* g){
  __builtin_amdgcn_global_load_lds(
      (const __attribute__((address_space(1))) unsigned int*)g,
      (__attribute__((address_space(3))) unsigned int*)lds, 16, 0, 0);
}

// ---- fused prep: [0,6144) xm = bf16(x*mask); [6144,8448) cast weights;
//      [8448,8452) Z[b] = masked-token count ------------------------------
#define PX_BLOCKS 6144            // BB*NN*CC/4/256
#define PW_BLOCKS 2304            // 4*CC*CC/4/256
__global__ void prep_all(const float* __restrict__ x, const float* __restrict__ mask,
                         const float* __restrict__ wq, const float* __restrict__ wp,
                         unsigned short* __restrict__ xm,
                         unsigned short* __restrict__ oq, unsigned short* __restrict__ op,
                         float* __restrict__ zb){
  const int blk = blockIdx.x, t = threadIdx.x;
  if (blk < PX_BLOCKS){
    int i = blk * 256 + t;                         // float4 group index
    float4 v = ((const float4*)x)[i];
    float m = mask[i / 192];                       // 768/4 = 192 groups per row
    ushort4 o;
    o.x = f2bf(v.x * m); o.y = f2bf(v.y * m);
    o.z = f2bf(v.z * m); o.w = f2bf(v.w * m);
    *(ushort4*)&xm[i * 4] = o;
  } else if (blk < PX_BLOCKS + PW_BLOCKS){
    int i = (blk - PX_BLOCKS) * 256 + t;
    const int nq = (3 * CC * CC) / 4;
    const float4* s; unsigned short* d; int j;
    if (i < nq){ s = (const float4*)wq; d = oq; j = i; }
    else       { s = (const float4*)wp; d = op; j = i - nq; }
    float4 v = s[j];
    ushort4 o;
    o.x = f2bf(v.x); o.y = f2bf(v.y); o.z = f2bf(v.z); o.w = f2bf(v.w);
    *(ushort4*)&d[j * 4] = o;
  } else {
    int b = blk - (PX_BLOCKS + PW_BLOCKS);
    float s = 0.f;
    for (int i = t; i < NN; i += 256) s += mask[b * NN + i];
    #pragma unroll
    for (int off = 1; off < 64; off <<= 1) s += __shfl_xor(s, off);
    __shared__ float part[4];
    if ((t & 63) == 0) part[t >> 6] = s;
    __syncthreads();
    if (t == 0) zb[b] = (float)NN - (part[0] + part[1] + part[2] + part[3]);
  }
}

// ---- C = A(row-major [M,K]) * B^T (B row-major [Nn,K]), bf16 MFMA -------
template<int MODE>
__global__ __launch_bounds__(256) void gemm_bt(
    const unsigned short* __restrict__ A, const unsigned short* __restrict__ Bw,
    int Nn, int K,
    unsigned short* __restrict__ Qg, unsigned short* __restrict__ Kg,
    unsigned short* __restrict__ Vtg, float* __restrict__ Outg)
{
  __shared__ __align__(16) unsigned short As[128 * 32];
  __shared__ __align__(16) unsigned short Bs[128 * 32];
  const int t = threadIdx.x, lane = t & 63, wid = t >> 6;
  const int wr = wid >> 1, wc = wid & 1;
  const int bm = blockIdx.x, bn = blockIdx.y;
  const unsigned short* Ag = A  + (size_t)bm * 128 * K;
  const unsigned short* Bg = Bw + (size_t)bn * 128 * K;
  f32x4 acc[4][4] = {};
  const int srow = wid * 32 + (lane >> 2);
  const int scol = (lane & 3) * 8;
  char* AsB = (char*)As; char* BsB = (char*)Bs;
  const int ar = wr * 64 + (lane & 15);
  const int br = wc * 64 + (lane & 15);
  const int kk = (lane >> 4) * 8;

  for (int k0 = 0; k0 < K; k0 += 32){
    __syncthreads();
    gld16(AsB + wid * 2048        + lane * 16, Ag + (size_t)srow * K        + k0 + scol);
    gld16(AsB + wid * 2048 + 1024 + lane * 16, Ag + (size_t)(srow + 16) * K + k0 + scol);
    gld16(BsB + wid * 2048        + lane * 16, Bg + (size_t)srow * K        + k0 + scol);
    gld16(BsB + wid * 2048 + 1024 + lane * 16, Bg + (size_t)(srow + 16) * K + k0 + scol);
    __syncthreads();
    s16x8 af[4], bf[4];
    #pragma unroll
    for (int mi = 0; mi < 4; ++mi) af[mi] = *(const s16x8*)&As[(ar + mi * 16) * 32 + kk];
    #pragma unroll
    for (int ni = 0; ni < 4; ++ni) bf[ni] = *(const s16x8*)&Bs[(br + ni * 16) * 32 + kk];
    #pragma unroll
    for (int mi = 0; mi < 4; ++mi)
      #pragma unroll
      for (int ni = 0; ni < 4; ++ni)
        acc[mi][ni] = mfma16(af[mi], bf[ni], acc[mi][ni]);
  }

  const int row0 = bm * 128 + wr * 64;
  const int col0 = bn * 128 + wc * 64;
  if (MODE == 0){
    #pragma unroll
    for (int ni = 0; ni < 4; ++ni){
      int col = col0 + ni * 16 + (lane & 15);
      int s = col / CC, rem = col - s * CC;
      int h = rem >> 6, d = rem & 63;
      #pragma unroll
      for (int mi = 0; mi < 4; ++mi){
        int rbase = row0 + mi * 16 + ((lane >> 4) << 2);
        int b = rbase >> 11, tok0 = rbase & 2047;
        if (s == 2){
          ushort4 pk;
          pk.x = f2bf(acc[mi][ni][0]); pk.y = f2bf(acc[mi][ni][1]);
          pk.z = f2bf(acc[mi][ni][2]); pk.w = f2bf(acc[mi][ni][3]);
          *(ushort4*)&Vtg[((size_t)((b * HH + h) * DD + d) << 11) + tok0] = pk;
        } else {
          unsigned short* dst = (s == 0) ? Qg : Kg;
          float sc = (s == 0) ? QSCALE : 1.0f;
          size_t base = (((size_t)(b * HH + h) << 11) + tok0) * DD + d;
          #pragma unroll
          for (int r = 0; r < 4; ++r) dst[base + (size_t)r * DD] = f2bf(acc[mi][ni][r] * sc);
        }
      }
    }
  } else {
    #pragma unroll
    for (int ni = 0; ni < 4; ++ni){
      int col = col0 + ni * 16 + (lane & 15);
      #pragma unroll
      for (int mi = 0; mi < 4; ++mi){
        int rbase = row0 + mi * 16 + ((lane >> 4) << 2);
        #pragma unroll
        for (int r = 0; r < 4; ++r) Outg[(size_t)(rbase + r) * Nn + col] = acc[mi][ni][r];
      }
    }
  }
}

// exp2 + RNE pack via v_cvt_pk_bf16_f32; l accumulated as float2 (v_pk_add_f32)
__device__ __forceinline__ void packrow2(float s0, float s1, float s2, float s3,
                                         f32x2& l2, unsigned& d0, unsigned& d1){
  float p0 = fexp2(s0), p1 = fexp2(s1), p2 = fexp2(s2), p3 = fexp2(s3);
  f32x2 a = {p0, p1}, b = {p2, p3};
  l2 += a + b;
  asm("v_cvt_pk_bf16_f32 %0, %1, %2" : "=v"(d0) : "v"(p0), "v"(p1));
  asm("v_cvt_pk_bf16_f32 %0, %1, %2" : "=v"(d1) : "v"(p2), "v"(p3));
}

// ---- flash attention, no-max softmax, kv-split wave pairs ----------------
// EXACT round-3 structure (66.6 us verified best: single-buffer LDS,
// 2 barriers/iter, 3 blocks/CU) + XCD swizzle (r6: FETCH 105->18.5 MB) +
// setprio around MFMA clusters (single-variable add this round, m191 +4-7%).
// Schedule-change ledger: dbuf+T14 (r6) = +6us WORSE; no-LDS (r7) = 2.8x
// WORSE (uncoalesced L2 gathers, no intra-block sharing). Do not revisit.
__global__ __launch_bounds__(256, 3) void attn_kernel(
    const unsigned short* __restrict__ Qg, const unsigned short* __restrict__ Kg,
    const unsigned short* __restrict__ Vtg, const float* __restrict__ mask,
    const float* __restrict__ zb, unsigned short* __restrict__ Og)
{
  // main loop: Ks 64x72 (9216B) + Vts 64x72 (9216B)
  // epilogue alias: 8192 f32 (o partials) + 128 f32 (l partials) = 33280B
  __shared__ __align__(16) char smem[33280];
  unsigned short* Ks  = (unsigned short*)smem;
  unsigned short* Vts = (unsigned short*)(smem + 9216);   // BYTE offset
  float* fb = (float*)smem;
  __shared__ float maskS[128];

  const int t = threadIdx.x, lane = t & 63, w = t >> 6;
  const int lo5 = lane & 31, hi = lane >> 5, hi8 = hi * 8;
  const int pair = w >> 1, h2 = w & 1;

  // XCD-chunked swizzle: 768 blocks = 8 x 96; all 16 q-tiles of a (b,h)
  // group land on one XCD -> K/V L2-resident per XCD.
  int g = blockIdx.x + (NN / 128) * blockIdx.y;
  g = (g & 7) * 96 + (g >> 3);
  const int qt = g & 15, bh = g >> 4;
  const int b = bh / HH, h = bh % HH;
  const unsigned short* Qb  = Qg  + (size_t)bh * NN * DD;
  const unsigned short* Kb  = Kg  + (size_t)bh * NN * DD;
  const unsigned short* Vtb = Vtg + (size_t)bh * DD * NN;

  // Q fragments (B-operand of swapped QK^T), 2 q-groups of 32 rows
  const int qrow0 = qt * 128 + pair * 64 + lo5;
  s16x8 qf0[4], qf1[4];
  #pragma unroll
  for (int ds = 0; ds < 4; ++ds){
    qf0[ds] = *(const s16x8*)&Qb[(size_t)qrow0 * DD + ds * 16 + hi8];
    qf1[ds] = *(const s16x8*)&Qb[(size_t)(qrow0 + 32) * DD + ds * 16 + hi8];
  }
  if (t < 128) maskS[t] = mask[b * NN + qt * 128 + t];

  // staging: 64x64 tile, thread t handles rows r0, r0+32 (16B chunks)
  const int r0 = t >> 3, k8 = (t & 7) * 8;
  const int r1 = r0 + 32;

  f32x16 o00 = {}, o01 = {}, o10 = {}, o11 = {};   // [qgrp][d-half]
  f32x2 la0 = {0.f, 0.f}, la1 = {0.f, 0.f};

  s16x8 kA = *(const s16x8*)&Kb[(size_t)r0 * DD + k8];
  s16x8 kB = *(const s16x8*)&Kb[(size_t)r1 * DD + k8];
  s16x8 vA = *(const s16x8*)&Vtb[(size_t)r0 * NN + k8];
  s16x8 vB = *(const s16x8*)&Vtb[(size_t)(32 + r0) * NN + k8];

  const int kbase = (h2 * 32 + lo5) * 72 + hi8;     // K frag base (shorts)
  const int vcol  = h2 * 32 + hi8;                  // V frag col base

  for (int tt = 0; tt < NN / 64; ++tt){
    *(s16x8*)&Ks [r0 * 72 + k8] = kA;
    *(s16x8*)&Ks [r1 * 72 + k8] = kB;
    *(s16x8*)&Vts[r0 * 72 + k8] = vA;
    *(s16x8*)&Vts[r1 * 72 + k8] = vB;
    __syncthreads();
    if (tt + 1 < NN / 64){
      int nk = (tt + 1) * 64;
      kA = *(const s16x8*)&Kb[(size_t)(nk + r0) * DD + k8];
      kB = *(const s16x8*)&Kb[(size_t)(nk + r1) * DD + k8];
      vA = *(const s16x8*)&Vtb[(size_t)r0 * NN + nk + k8];
      vB = *(const s16x8*)&Vtb[(size_t)(32 + r0) * NN + nk + k8];
    }

    // QK^T swapped (kv half only): S^T[kv][q], col=q=lo5
    f32x16 s0 = {}, s1 = {};
    __builtin_amdgcn_s_setprio(1);
    #pragma unroll
    for (int ds = 0; ds < 4; ++ds){
      s16x8 kf = *(const s16x8*)&Ks[kbase + ds * 16];
      s0 = mfma32(kf, qf0[ds], s0);
      s1 = mfma32(kf, qf1[ds], s1);
    }
    __builtin_amdgcn_s_setprio(0);

    unsigned pdw0[8], pdw1[8];
    #pragma unroll
    for (int c = 0; c < 4; ++c){
      packrow2(s0[4*c+0], s0[4*c+1], s0[4*c+2], s0[4*c+3], la0, pdw0[2*c], pdw0[2*c+1]);
      packrow2(s1[4*c+0], s1[4*c+1], s1[4*c+2], s1[4*c+3], la1, pdw1[2*c], pdw1[2*c+1]);
    }

    // P-exchange + PV (2 k-slices of 16 in this wave's kv half)
    __builtin_amdgcn_s_setprio(1);
    #pragma unroll
    for (int sl = 0; sl < 2; ++sl){
      const int bb2 = sl * 4;
      unsigned X0 = pdw0[bb2+0], X1 = pdw0[bb2+1], Y0 = pdw0[bb2+2], Y1 = pdw0[bb2+3];
      asm("s_nop 0\n\tv_permlane32_swap_b32 %0, %1" : "+v"(X0), "+v"(Y0));
      asm("s_nop 0\n\tv_permlane32_swap_b32 %0, %1" : "+v"(X1), "+v"(Y1));
      union { unsigned u[4]; s16x8 v; } pa0;
      pa0.u[0] = X0; pa0.u[1] = X1; pa0.u[2] = Y0; pa0.u[3] = Y1;
      unsigned Z0 = pdw1[bb2+0], Z1 = pdw1[bb2+1], W0 = pdw1[bb2+2], W1 = pdw1[bb2+3];
      asm("s_nop 0\n\tv_permlane32_swap_b32 %0, %1" : "+v"(Z0), "+v"(W0));
      asm("s_nop 0\n\tv_permlane32_swap_b32 %0, %1" : "+v"(Z1), "+v"(W1));
      union { unsigned u[4]; s16x8 v; } pa1;
      pa1.u[0] = Z0; pa1.u[1] = Z1; pa1.u[2] = W0; pa1.u[3] = W1;
      s16x8 vfA = *(const s16x8*)&Vts[(size_t)lo5 * 72 + vcol + sl * 16];        // d 0..31
      s16x8 vfB = *(const s16x8*)&Vts[(size_t)(32 + lo5) * 72 + vcol + sl * 16]; // d 32..63
      o00 = mfma32(pa0.v, vfA, o00);
      o01 = mfma32(pa0.v, vfB, o01);
      o10 = mfma32(pa1.v, vfA, o10);
      o11 = mfma32(pa1.v, vfB, o11);
    }
    __builtin_amdgcn_s_setprio(0);
    __syncthreads();
  }

  // l partial per q (this wave's kv half): sum own 16 + partner-hi 16
  float lw0 = la0.x + la0.y; lw0 += __shfl_xor(lw0, 32);
  float lw1 = la1.x + la1.y; lw1 += __shfl_xor(lw1, 32);

  __syncthreads();                       // main-loop LDS reads done
  if (h2 == 1){                          // odd wave: publish partials
    const int ob = pair * 4096 + lane * 16;
    *(f32x16*)&fb[ob +    0] = o00;
    *(f32x16*)&fb[ob + 1024] = o01;
    *(f32x16*)&fb[ob + 2048] = o10;
    *(f32x16*)&fb[ob + 3072] = o11;
    if (hi == 0){
      fb[8192 + pair * 64 + lo5]      = lw0;
      fb[8192 + pair * 64 + 32 + lo5] = lw1;
    }
  }
  __syncthreads();
  if (h2 == 0){                          // even wave: combine + normalize + store
    const int ob = pair * 4096 + lane * 16;
    o00 += *(const f32x16*)&fb[ob +    0];
    o01 += *(const f32x16*)&fb[ob + 1024];
    o10 += *(const f32x16*)&fb[ob + 2048];
    o11 += *(const f32x16*)&fb[ob + 3072];
    float Zbv = zb[b];
    lw0 = lw0 + fb[8192 + pair * 64 + lo5]      - Zbv;
    lw1 = lw1 + fb[8192 + pair * 64 + 32 + lo5] - Zbv;
    #pragma unroll
    for (int i = 0; i < 16; ++i){
      int q_ = (i & 3) + 8 * (i >> 2) + 4 * hi;
      int qg0 = qt * 128 + pair * 64 + q_;
      float lq0 = __shfl(lw0, q_);
      float mq0 = maskS[pair * 64 + q_];
      float inv0 = (mq0 != 0.f) ? (mq0 / lq0) : 0.f;
      size_t base0 = ((size_t)b * NN + qg0) * CC + h * DD + lo5;
      Og[base0]      = f2bf(o00[i] * inv0);
      Og[base0 + 32] = f2bf(o01[i] * inv0);
      float lq1 = __shfl(lw1, q_);
      float mq1 = maskS[pair * 64 + 32 + q_];
      float inv1 = (mq1 != 0.f) ? (mq1 / lq1) : 0.f;
      size_t base1 = base0 + (size_t)32 * CC;
      Og[base1]      = f2bf(o10[i] * inv1);
      Og[base1 + 32] = f2bf(o11[i] * inv1);
    }
  }
}

extern "C" void kernel_launch(void* const* d_in, const int* in_sizes, int n_in,
                              void* d_out, int out_size, void* d_ws, size_t ws_size,
                              hipStream_t stream){
  const float* x     = (const float*)d_in[0];
  const float* mask  = (const float*)d_in[1];
  const float* wqkv  = (const float*)d_in[2];
  const float* wproj = (const float*)d_in[3];
  float* out = (float*)d_out;
  char* ws = (char*)d_ws;
  size_t off = 0;
  auto alloc = [&](size_t bytes) -> void* {
    void* p = ws + off; off += (bytes + 255) & ~(size_t)255; return p;
  };
  unsigned short* xm  = (unsigned short*)alloc((size_t)BB * NN * CC * 2);
  unsigned short* wqb = (unsigned short*)alloc((size_t)3 * CC * CC * 2);
  unsigned short* wpb = (unsigned short*)alloc((size_t)CC * CC * 2);
  unsigned short* Qg  = (unsigned short*)alloc((size_t)BB * HH * NN * DD * 2);
  unsigned short* Kg  = (unsigned short*)alloc((size_t)BB * HH * NN * DD * 2);
  unsigned short* Vtg = (unsigned short*)alloc((size_t)BB * HH * NN * DD * 2);
  unsigned short* Og  = (unsigned short*)alloc((size_t)BB * NN * CC * 2);
  float* zbuf         = (float*)alloc(BB * sizeof(float));

  hipLaunchKernelGGL(prep_all, dim3(PX_BLOCKS + PW_BLOCKS + BB), dim3(256), 0, stream,
                     x, mask, wqkv, wproj, xm, wqb, wpb, zbuf);
  hipLaunchKernelGGL(gemm_bt<0>, dim3(BB * NN / 128, 3 * CC / 128), dim3(256), 0, stream,
                     xm, wqb, 3 * CC, CC, Qg, Kg, Vtg, (float*)nullptr);
  hipLaunchKernelGGL(attn_kernel, dim3(NN / 128, BB * HH), dim3(256), 0, stream,
                     Qg, Kg, Vtg, mask, zbuf, Og);
  hipLaunchKernelGGL(gemm_bt<1>, dim3(BB * NN / 128, CC / 128), dim3(256), 0, stream,
                     Og, wpb, CC, CC, (unsigned short*)nullptr, (unsigned short*)nullptr,
                     (unsigned short*)nullptr, out);
}